// Round 9
// baseline (3314332.812 us; speedup 1.0000x reference)
//
#include <hip/hip_runtime.h>
#include <stdint.h>

// ---------------- problem constants ----------------
#define B_   256
#define T_   512
#define CIN  64
#define H_   256
#define G4   1024   // 4*H
#define NC   6

// ---------------- WG geometry ----------------------
#define MB   32               // batch rows per WG
#define NHU  16               // hidden units per WG
#define NBG  (B_/MB)          // 8 batch groups
#define NHG  (H_/NHU)         // 16 hidden groups
#define NWG  (NBG*NHG)        // 128 workgroups

typedef __bf16 bf16x8 __attribute__((ext_vector_type(8)));
typedef __bf16 bf16x4 __attribute__((ext_vector_type(4)));
typedef float  f32x4  __attribute__((ext_vector_type(4)));

// ---------------- workspace layout (bytes) ---------
#define OFF_XBF   ((size_t)0)
#define SZ_XBF    ((size_t)B_*T_*CIN*2)          // 16 MB
#define OFF_W0X   (OFF_XBF + SZ_XBF)
#define SZ_W0X    ((size_t)G4*CIN*2)             // 128 KB
#define OFF_W0H   (OFF_W0X + SZ_W0X)
#define SZ_WH     ((size_t)G4*H_*2)              // 512 KB
#define OFF_W1X   (OFF_W0H + SZ_WH)
#define OFF_W1H   (OFF_W1X + SZ_WH)
#define OFF_B0    (OFF_W1H + SZ_WH)
#define OFF_B1    (OFF_B0 + 4096)
#define OFF_APUB  (OFF_B1 + 4096)
#define SZ_PUB    ((size_t)2*B_*H_*2)            // 256 KB (2 slots)
#define OFF_BPUB  (OFF_APUB + SZ_PUB)
#define OFF_SYNC  (OFF_BPUB + SZ_PUB)
#define SYNC_WORDS 512
// sync word map: stamps: bg lines at [bg*64 .. bg*64+15] (bg 0..7 -> words 0..463)
//                registration: counts at [480..495], total at [508]

#define DYN_LDS_ELEMS (4096 + 3*16384)           // 53248 bf16
#define DYN_LDS_BYTES (DYN_LDS_ELEMS*2)          // 106496 B

__device__ __forceinline__ f32x4 MFMA(bf16x8 a, bf16x8 b, f32x4 c) {
  return __builtin_amdgcn_mfma_f32_16x16x32_bf16(a, b, c, 0, 0, 0);
}
__device__ __forceinline__ float fsig(float x) { return 1.f/(1.f + __expf(-x)); }
__device__ __forceinline__ float ftanh_(float x) {
  float xx = fminf(fmaxf(x, -15.f), 15.f);
  float t = __expf(2.f*xx);
  return (t-1.f)/(t+1.f);
}

// batched 8x16B coherent loads; fast = XCD-L2 (sc0), slow = MALL (sc0 sc1)
__device__ __forceinline__ void load8_c(const __bf16* b, bf16x8 (&r)[8], bool fast) {
  const __bf16 *p0=b,      *p1=b+32,  *p2=b+64,  *p3=b+96,
               *p4=b+128,  *p5=b+160, *p6=b+192, *p7=b+224;
  if (fast) {
    asm volatile(
      "global_load_dwordx4 %0, %8, off sc0\n\t"
      "global_load_dwordx4 %1, %9, off sc0\n\t"
      "global_load_dwordx4 %2, %10, off sc0\n\t"
      "global_load_dwordx4 %3, %11, off sc0\n\t"
      "global_load_dwordx4 %4, %12, off sc0\n\t"
      "global_load_dwordx4 %5, %13, off sc0\n\t"
      "global_load_dwordx4 %6, %14, off sc0\n\t"
      "global_load_dwordx4 %7, %15, off sc0"
      : "=&v"(r[0]), "=&v"(r[1]), "=&v"(r[2]), "=&v"(r[3]),
        "=&v"(r[4]), "=&v"(r[5]), "=&v"(r[6]), "=&v"(r[7])
      : "v"(p0), "v"(p1), "v"(p2), "v"(p3), "v"(p4), "v"(p5), "v"(p6), "v"(p7)
      : "memory");
  } else {
    asm volatile(
      "global_load_dwordx4 %0, %8, off sc0 sc1\n\t"
      "global_load_dwordx4 %1, %9, off sc0 sc1\n\t"
      "global_load_dwordx4 %2, %10, off sc0 sc1\n\t"
      "global_load_dwordx4 %3, %11, off sc0 sc1\n\t"
      "global_load_dwordx4 %4, %12, off sc0 sc1\n\t"
      "global_load_dwordx4 %5, %13, off sc0 sc1\n\t"
      "global_load_dwordx4 %6, %14, off sc0 sc1\n\t"
      "global_load_dwordx4 %7, %15, off sc0 sc1"
      : "=&v"(r[0]), "=&v"(r[1]), "=&v"(r[2]), "=&v"(r[3]),
        "=&v"(r[4]), "=&v"(r[5]), "=&v"(r[6]), "=&v"(r[7])
      : "v"(p0), "v"(p1), "v"(p2), "v"(p3), "v"(p4), "v"(p5), "v"(p6), "v"(p7)
      : "memory");
  }
}
__device__ __forceinline__ void waitv0() { asm volatile("s_waitcnt vmcnt(0)" ::: "memory"); }
__device__ __forceinline__ void sbar0()  { __builtin_amdgcn_sched_barrier(0); }

// one-wave, one-line rendezvous poll (round-7 semantics), scope-parameterized.
// Fast path carries a fail-fast iteration cap: a broken-semantics run terminates
// with visibly wrong output instead of hanging the harness.
__device__ __forceinline__ void poll16(const unsigned* fb, unsigned tgt, bool fast) {
  const unsigned* p = fb + (threadIdx.x & 15);
  const unsigned cap = fast ? (1u<<16) : (1u<<24);
  for (unsigned it = 0; it < cap; ++it) {
    unsigned v;
    if (fast)
      asm volatile("global_load_dword %0, %1, off sc0\n\ts_waitcnt vmcnt(0)"
                   : "=&v"(v) : "v"(p) : "memory");
    else
      asm volatile("global_load_dword %0, %1, off sc0 sc1\n\ts_waitcnt vmcnt(0)"
                   : "=&v"(v) : "v"(p) : "memory");
    if (__ballot(v >= tgt) == ~0ull) return;
    if (!fast) __builtin_amdgcn_s_sleep(1);
  }
}
__device__ __forceinline__ void store_stamp(unsigned* p, unsigned v, bool fast) {
  if (fast) asm volatile("global_store_dword %0, %1, off sc0"     :: "v"(p), "v"(v) : "memory");
  else      asm volatile("global_store_dword %0, %1, off sc0 sc1" :: "v"(p), "v"(v) : "memory");
}
// write-through 2B publish store
__device__ __forceinline__ void store_h16(__bf16* p, float v, bool fast) {
  __bf16 h = (__bf16)v;
  unsigned u = (unsigned)__builtin_bit_cast(unsigned short, h);
  if (fast) asm volatile("global_store_short %0, %1, off sc0"     :: "v"(p), "v"(u) : "memory");
  else      asm volatile("global_store_short %0, %1, off sc0 sc1" :: "v"(p), "v"(u) : "memory");
}

// ---------------- prep: x -> bf16 ------------------
__global__ void k_prep_x(const float* __restrict__ x, __bf16* __restrict__ xbf) {
  int i = blockIdx.x * blockDim.x + threadIdx.x;
  const int n4 = (B_*T_*CIN)/4;
  if (i >= n4) return;
  float4 v = reinterpret_cast<const float4*>(x)[i];
  bf16x4 o;
  o[0] = (__bf16)v.x; o[1] = (__bf16)v.y; o[2] = (__bf16)v.z; o[3] = (__bf16)v.w;
  reinterpret_cast<bf16x4*>(xbf)[i] = o;
}

// ---------------- prep: weights into MFMA-fragment order ----------------
// target layout per matrix: [hj][ct][ks][sub][col][j]  (j=8 contiguous bf16)
// element = W[g=ct*256+hj*16+col][k=ks*32+sub*8+j]
__global__ void k_prep_w(const float* __restrict__ Wih0, const float* __restrict__ Whh0,
                         const float* __restrict__ Wih1, const float* __restrict__ Whh1,
                         __bf16* __restrict__ w0x, __bf16* __restrict__ w0h,
                         __bf16* __restrict__ w1x, __bf16* __restrict__ w1h) {
  int e = blockIdx.x * blockDim.x + threadIdx.x;
  const int E0 = G4*CIN, E1 = G4*H_;
  const float* W; __bf16* dst; int K; int idx;
  if      (e < E0)        { W = Wih0; dst = w0x; K = CIN; idx = e; }
  else if (e < E0+E1)     { W = Whh0; dst = w0h; K = H_;  idx = e - E0; }
  else if (e < E0+2*E1)   { W = Wih1; dst = w1x; K = H_;  idx = e - E0 - E1; }
  else if (e < E0+3*E1)   { W = Whh1; dst = w1h; K = H_;  idx = e - E0 - 2*E1; }
  else return;
  const int kb = K >> 5;                  // K/32
  int j   = idx & 7;
  int cl  = (idx >> 3) & 15;
  int sb  = (idx >> 7) & 3;
  int ks  = (idx >> 9) % kb;
  int ct  = (idx / (512*kb)) & 3;
  int hj  =  idx / (2048*kb);
  int g  = ct*256 + hj*16 + cl;
  int kk = ks*32 + sb*8 + j;
  dst[idx] = (__bf16)W[(size_t)g*K + kk];
}

// ---------------- prep: biases, zero pub buffers, zero sync ----------------
__global__ void k_prep_misc(const float* __restrict__ bih0, const float* __restrict__ bhh0,
                            const float* __restrict__ bih1, const float* __restrict__ bhh1,
                            float* __restrict__ bias0, float* __restrict__ bias1,
                            unsigned* __restrict__ zpub, unsigned* __restrict__ syncw) {
  int i = blockIdx.x * blockDim.x + threadIdx.x;
  if (i < G4) bias0[i] = bih0[i] + bhh0[i];
  else if (i < 2*G4) { int j = i - G4; bias1[j] = bih1[j] + bhh1[j]; }
  const int PW = (int)((2*SZ_PUB)/4);
  int zi = i - 2*G4;
  if (zi >= 0 && zi < PW) zpub[zi] = 0u;   // apub+bpub contiguous
  if (i < SYNC_WORDS) syncw[i] = 0u;
}

// ---------------- persistent pipelined LSTM ----------------
__global__ void __launch_bounds__(256, 1) k_lstm(
    const __bf16* __restrict__ xbf,
    const __bf16* __restrict__ w0x_g, const __bf16* __restrict__ w0h_g,
    const __bf16* __restrict__ w1x_g, const __bf16* __restrict__ w1h_g,
    const float* __restrict__ bias0, const float* __restrict__ bias1,
    __bf16* __restrict__ apub, __bf16* __restrict__ bpub,
    unsigned* __restrict__ sync,
    const float* __restrict__ Wfc, const float* __restrict__ bfc,
    float* __restrict__ out)
{
  extern __shared__ __bf16 lds[];
  __bf16* l0x = lds;                 // 4096  elems
  __bf16* l0h = lds + 4096;          // 16384
  __bf16* l1x = lds + 20480;         // 16384
  __bf16* l1h = lds + 36864;         // 16384
  __shared__ float s_log[MB][NC];
  __shared__ int s_fastsh, s_bgsh, s_hjsh;

  const int tid   = threadIdx.x;
  const int bid   = blockIdx.x;

  // ---- one-time XCD-placement registration & uniform verdict ----
  // HW truth via XCC_ID register (id 20, gfx940+). All-slow fallback if any
  // XCD doesn't hold exactly 16 WGs -> no mixed-scope bg can ever exist.
  if (tid == 0) {
    unsigned xcd;
    asm volatile("s_getreg_b32 %0, hwreg(20, 0, 32)" : "=s"(xcd));
    xcd &= 15u;
    unsigned* cnts = sync + 480;
    unsigned rank = __hip_atomic_fetch_add(cnts + xcd, 1u,
                      __ATOMIC_RELAXED, __HIP_MEMORY_SCOPE_AGENT);
    __hip_atomic_fetch_add(sync + 508, 1u,
                      __ATOMIC_RELEASE, __HIP_MEMORY_SCOPE_AGENT);
    while (__hip_atomic_load(sync + 508, __ATOMIC_ACQUIRE,
                             __HIP_MEMORY_SCOPE_AGENT) < (unsigned)NWG)
      __builtin_amdgcn_s_sleep(2);
    int ok = 1;
    for (int i = 0; i < 16; ++i) {
      unsigned c = __hip_atomic_load(cnts + i, __ATOMIC_RELAXED,
                                     __HIP_MEMORY_SCOPE_AGENT);
      if (i < 8) { if (c != 16u) ok = 0; }
      else if (c != 0u) ok = 0;
    }
    s_fastsh = ok;
    s_bgsh = ok ? (int)xcd  : (bid & 7);
    s_hjsh = ok ? (int)rank : (bid >> 3);
  }
  __syncthreads();
  const bool fast = (s_fastsh != 0);
  const int  bg   = s_bgsh;          // fast: == my XCD -> exchange stays in L2
  const int  hj   = s_hjsh;

  const int wave  = tid >> 6;
  const int lane  = tid & 63;
  const int layer = wave >> 1;       // waves 0,1 -> layer0 ; waves 2,3 -> layer1
  const int mt    = wave & 1;
  const int col   = lane & 15;       // MFMA A-row / D-col index
  const int sub   = lane >> 4;       // MFMA k-group
  const int brow  = bg*MB + mt*16;

  unsigned* stline = sync + (size_t)bg*64;   // this bg's 16 stamp words (one line)
  unsigned* myst   = stline + hj;

  // stage weights LDS-resident for the whole run
  {
    const uint4* s; uint4* d;
    s = (const uint4*)(w0x_g + (size_t)hj*4096);  d = (uint4*)l0x;
    for (int i = tid; i < 512;  i += 256) d[i] = s[i];
    s = (const uint4*)(w0h_g + (size_t)hj*16384); d = (uint4*)l0h;
    for (int i = tid; i < 2048; i += 256) d[i] = s[i];
    s = (const uint4*)(w1x_g + (size_t)hj*16384); d = (uint4*)l1x;
    for (int i = tid; i < 2048; i += 256) d[i] = s[i];
    s = (const uint4*)(w1h_g + (size_t)hj*16384); d = (uint4*)l1h;
    for (int i = tid; i < 2048; i += 256) d[i] = s[i];
  }
  __syncthreads();

  // per-lane gate biases (unit = hj*16+col), per this wave's layer
  float bs0, bs1, bs2, bs3;
  {
    const float* bp = layer ? bias1 : bias0;
    bs0 = bp[0*256 + hj*16 + col];
    bs1 = bp[1*256 + hj*16 + col];
    bs2 = bp[2*256 + hj*16 + col];
    bs3 = bp[3*256 + hj*16 + col];
  }
  float cst[4] = {0.f, 0.f, 0.f, 0.f};   // c-state for this lane's 4 (row,unit) cells

  for (int k = 0; k <= T_; ++k) {
    const __bf16* a_prev = apub + (size_t)((k+1)&1)*(B_*H_);
    const __bf16* b_prev = bpub + (size_t)((k+1)&1)*(B_*H_);
    __bf16* a_cur = apub + (size_t)(k&1)*(B_*H_);
    __bf16* b_cur = bpub + (size_t)(k&1)*(B_*H_);
    const bool act0 = (layer == 0) && (k < T_);
    const bool act1 = (layer == 1) && (k >= 1);
    f32x4 acc0 = {0,0,0,0}, acc1 = {0,0,0,0}, acc2 = {0,0,0,0}, acc3 = {0,0,0,0};

    // phase A (no dependence on published data): x-input GEMM, K=64
    if (act0) {
      const __bf16* xr = xbf + ((size_t)(brow+col)*T_ + k)*CIN + sub*8;
      const __bf16* wb = l0x + sub*128 + col*8;
#pragma unroll
      for (int ks = 0; ks < 2; ++ks) {
        bf16x8 a = *(const bf16x8*)(xr + ks*32);
        acc0 = MFMA(a, *(const bf16x8*)(wb + ks*512 +    0), acc0);
        acc1 = MFMA(a, *(const bf16x8*)(wb + ks*512 + 1024), acc1);
        acc2 = MFMA(a, *(const bf16x8*)(wb + ks*512 + 2048), acc2);
        acc3 = MFMA(a, *(const bf16x8*)(wb + ks*512 + 3072), acc3);
      }
    }

    // rendezvous: wave 0 polls the bg's 16 stamps, barrier releases the WG
    if (k > 0) {
      if (tid < 64) poll16(stline, (unsigned)k, fast);
      __syncthreads();
    }

    // phase B: recurrent GEMMs (operands via coherent loads)
    if (act0) {            // gates0 += a_{k-1} @ Whh0^T
      bf16x8 ra[8];
      load8_c(a_prev + (size_t)(brow+col)*H_ + sub*8, ra, fast);
      waitv0(); sbar0();
      const __bf16* wb = l0h + sub*128 + col*8;
#pragma unroll
      for (int ks = 0; ks < 8; ++ks) {
        acc0 = MFMA(ra[ks], *(const bf16x8*)(wb + ks*512 +     0), acc0);
        acc1 = MFMA(ra[ks], *(const bf16x8*)(wb + ks*512 +  4096), acc1);
        acc2 = MFMA(ra[ks], *(const bf16x8*)(wb + ks*512 +  8192), acc2);
        acc3 = MFMA(ra[ks], *(const bf16x8*)(wb + ks*512 + 12288), acc3);
      }
    } else if (act1) {     // gates1 = a_{k-1} @ Wih1^T + b_{k-2} @ Whh1^T
      bf16x8 ra[8], rb[8];
      load8_c(a_prev + (size_t)(brow+col)*H_ + sub*8, ra, fast);
      load8_c(b_prev + (size_t)(brow+col)*H_ + sub*8, rb, fast);
      waitv0(); sbar0();
      const __bf16* w1 = l1x + sub*128 + col*8;
      const __bf16* w2 = l1h + sub*128 + col*8;
#pragma unroll
      for (int ks = 0; ks < 8; ++ks) {
        acc0 = MFMA(ra[ks], *(const bf16x8*)(w1 + ks*512 +     0), acc0);
        acc1 = MFMA(ra[ks], *(const bf16x8*)(w1 + ks*512 +  4096), acc1);
        acc2 = MFMA(ra[ks], *(const bf16x8*)(w1 + ks*512 +  8192), acc2);
        acc3 = MFMA(ra[ks], *(const bf16x8*)(w1 + ks*512 + 12288), acc3);
      }
#pragma unroll
      for (int ks = 0; ks < 8; ++ks) {
        acc0 = MFMA(rb[ks], *(const bf16x8*)(w2 + ks*512 +     0), acc0);
        acc1 = MFMA(rb[ks], *(const bf16x8*)(w2 + ks*512 +  4096), acc1);
        acc2 = MFMA(rb[ks], *(const bf16x8*)(w2 + ks*512 +  8192), acc2);
        acc3 = MFMA(rb[ks], *(const bf16x8*)(w2 + ks*512 + 12288), acc3);
      }
    }

    // elementwise LSTM cell + publish h (write-through bf16)
    if (act0 || act1) {
      __bf16* dst  = act0 ? a_cur : b_cur;
      __bf16* drow = dst + (size_t)(brow + sub*4)*H_ + hj*NHU + col;
#pragma unroll
      for (int q = 0; q < 4; ++q) {
        float gi = acc0[q] + bs0;
        float gf = acc1[q] + bs1;
        float gg = acc2[q] + bs2;
        float go = acc3[q] + bs3;
        float si = fsig(gi), sf = fsig(gf), sg = ftanh_(gg), so = fsig(go);
        float c = sf*cst[q] + si*sg;
        cst[q] = c;
        store_h16(drow + (size_t)q*H_, so * ftanh_(c), fast);
      }
    }

    // arrive: drain own stores; barrier = whole WG drained; one stamp store
    waitv0();
    __syncthreads();
    if (tid == 0) store_stamp(myst, (unsigned)(k + 1), fast);
  }

  // ---------------- final FC + softmax (one WG per batch group) ----------------
  if (hj == 0) {
    if (tid < 64) poll16(stline, (unsigned)(T_ + 1), fast);
    __syncthreads();
    // h1[T-1] lives in bpub slot (T_ & 1) == 0
    if (tid < MB*NC) {
      int r = tid / NC, cl = tid % NC;
      const __bf16* hr = bpub + (size_t)(bg*MB + r)*H_;
      const float*  wr = Wfc + (size_t)cl*H_;
      float s = bfc[cl];
      for (int c8 = 0; c8 < 32; ++c8) {
        bf16x8 v;
        const __bf16* p = hr + c8*8;
        if (fast)
          asm volatile("global_load_dwordx4 %0, %1, off sc0\n\ts_waitcnt vmcnt(0)"
                       : "=&v"(v) : "v"(p) : "memory");
        else
          asm volatile("global_load_dwordx4 %0, %1, off sc0 sc1\n\ts_waitcnt vmcnt(0)"
                       : "=&v"(v) : "v"(p) : "memory");
#pragma unroll
        for (int j = 0; j < 8; ++j) s = fmaf((float)v[j], wr[c8*8+j], s);
      }
      s_log[r][cl] = s;
    }
    __syncthreads();
    if (tid < MB) {
      float mx = s_log[tid][0];
#pragma unroll
      for (int c2 = 1; c2 < NC; ++c2) mx = fmaxf(mx, s_log[tid][c2]);
      float e[NC]; float se = 0.f;
#pragma unroll
      for (int c2 = 0; c2 < NC; ++c2) { e[c2] = __expf(s_log[tid][c2] - mx); se += e[c2]; }
      float inv = 1.f/se;
#pragma unroll
      for (int c2 = 0; c2 < NC; ++c2) out[(size_t)(bg*MB + tid)*NC + c2] = e[c2]*inv;
    }
  }
}

// ---------------- host launcher ----------------
extern "C" void kernel_launch(void* const* d_in, const int* in_sizes, int n_in,
                              void* d_out, int out_size, void* d_ws, size_t ws_size,
                              hipStream_t stream) {
  const float* x    = (const float*)d_in[0];
  const float* Wih0 = (const float*)d_in[1];
  const float* Whh0 = (const float*)d_in[2];
  const float* bih0 = (const float*)d_in[3];
  const float* bhh0 = (const float*)d_in[4];
  const float* Wih1 = (const float*)d_in[5];
  const float* Whh1 = (const float*)d_in[6];
  const float* bih1 = (const float*)d_in[7];
  const float* bhh1 = (const float*)d_in[8];
  const float* Wfc  = (const float*)d_in[9];
  const float* bfc  = (const float*)d_in[10];
  float* out = (float*)d_out;
  char*  ws  = (char*)d_ws;

  __bf16* xbf  = (__bf16*)(ws + OFF_XBF);
  __bf16* w0x  = (__bf16*)(ws + OFF_W0X);
  __bf16* w0h  = (__bf16*)(ws + OFF_W0H);
  __bf16* w1x  = (__bf16*)(ws + OFF_W1X);
  __bf16* w1h  = (__bf16*)(ws + OFF_W1H);
  float*  b0   = (float*) (ws + OFF_B0);
  float*  b1   = (float*) (ws + OFF_B1);
  __bf16* apub = (__bf16*)(ws + OFF_APUB);
  __bf16* bpub = (__bf16*)(ws + OFF_BPUB);
  unsigned* syncw = (unsigned*)(ws + OFF_SYNC);

  {
    const int n4 = (B_*T_*CIN)/4;
    k_prep_x<<<(n4 + 255)/256, 256, 0, stream>>>(x, xbf);
  }
  {
    const int tot = G4*CIN + 3*G4*H_;
    k_prep_w<<<(tot + 255)/256, 256, 0, stream>>>(Wih0, Whh0, Wih1, Whh1, w0x, w0h, w1x, w1h);
  }
  {
    const int tot = 2*G4 + (int)((2*SZ_PUB)/4);
    k_prep_misc<<<(tot + 255)/256, 256, 0, stream>>>(bih0, bhh0, bih1, bhh1, b0, b1,
                                                     (unsigned*)apub, syncw);
  }
  (void)hipFuncSetAttribute((const void*)k_lstm,
                            hipFuncAttributeMaxDynamicSharedMemorySize, DYN_LDS_BYTES);
  k_lstm<<<NWG, 256, DYN_LDS_BYTES, stream>>>(xbf, w0x, w0h, w1x, w1h, b0, b1,
                                              apub, bpub, syncw, Wfc, bfc, out);
}

// Round 10
// 3598.132 us; speedup vs baseline: 921.1260x; 921.1260x over previous
//
#include <hip/hip_runtime.h>
#include <stdint.h>

// ---------------- problem constants ----------------
#define B_   256
#define T_   512
#define CIN  64
#define H_   256
#define G4   1024   // 4*H
#define NC   6

// ---------------- WG geometry ----------------------
#define MB   32               // batch rows per WG
#define NHU  16               // hidden units per WG
#define NBG  (B_/MB)          // 8 batch groups
#define NHG  (H_/NHU)         // 16 hidden groups
#define NWG  (NBG*NHG)        // 128 workgroups
#define SLOTS 4               // pub ring depth (WAR-safe with end barrier)
#define SLOT_U32 (B_*H_)      // 65536 u32 per slot (4B per unit: tag<<16 | bf16)

typedef __bf16 bf16x8 __attribute__((ext_vector_type(8)));
typedef __bf16 bf16x4 __attribute__((ext_vector_type(4)));
typedef float  f32x4  __attribute__((ext_vector_type(4)));
typedef unsigned u32x4 __attribute__((ext_vector_type(4)));

// ---------------- workspace layout (bytes) ---------
#define OFF_XBF   ((size_t)0)
#define SZ_XBF    ((size_t)B_*T_*CIN*2)          // 16 MB
#define OFF_W0X   (OFF_XBF + SZ_XBF)
#define SZ_W0X    ((size_t)G4*CIN*2)             // 128 KB
#define OFF_W0H   (OFF_W0X + SZ_W0X)
#define SZ_WH     ((size_t)G4*H_*2)              // 512 KB
#define OFF_W1X   (OFF_W0H + SZ_WH)
#define OFF_W1H   (OFF_W1X + SZ_WH)
#define OFF_B0    (OFF_W1H + SZ_WH)
#define OFF_B1    (OFF_B0 + 4096)
#define OFF_APUB  (OFF_B1 + 4096)
#define SZ_PUB    ((size_t)SLOTS*SLOT_U32*4)     // 1 MB per array
#define OFF_BPUB  (OFF_APUB + SZ_PUB)

#define DYN_LDS_ELEMS (4096 + 3*16384)           // 53248 bf16
#define DYN_LDS_BYTES (DYN_LDS_ELEMS*2)          // 106496 B

#define POLL_CAP 16384                           // fail-fast: wrong output, never a hang

__device__ __forceinline__ f32x4 MFMA(bf16x8 a, bf16x8 b, f32x4 c) {
  return __builtin_amdgcn_mfma_f32_16x16x32_bf16(a, b, c, 0, 0, 0);
}
__device__ __forceinline__ float fsig(float x) { return 1.f/(1.f + __expf(-x)); }
__device__ __forceinline__ float ftanh_(float x) {
  float xx = fminf(fmaxf(x, -15.f), 15.f);
  float t = __expf(2.f*xx);
  return (t-1.f)/(t+1.f);
}

__device__ __forceinline__ u32x4 ld4_c(const unsigned* p) {
  u32x4 v;
  asm volatile("global_load_dwordx4 %0, %1, off sc0 sc1"
               : "=&v"(v) : "v"(p) : "memory");
  return v;
}
__device__ __forceinline__ void st4_c(unsigned* p, unsigned v) {
  asm volatile("global_store_dword %0, %1, off sc0 sc1" :: "v"(p), "v"(v) : "memory");
}
__device__ __forceinline__ void waitv0() { asm volatile("s_waitcnt vmcnt(0)" ::: "memory"); }
__device__ __forceinline__ void sbar0()  { __builtin_amdgcn_sched_barrier(0); }

// pack 8 tagged u32 (low16 = bf16) into one MFMA A-fragment
__device__ __forceinline__ bf16x8 packfrag(u32x4 a, u32x4 b) {
  union { unsigned u[4]; bf16x8 v; } r;
  r.u[0] = (a[0] & 0xffffu) | (a[1] << 16);
  r.u[1] = (a[2] & 0xffffu) | (a[3] << 16);
  r.u[2] = (b[0] & 0xffffu) | (b[1] << 16);
  r.u[3] = (b[2] & 0xffffu) | (b[3] << 16);
  return r.v;
}

// self-synchronizing row load: 16 dwordx4 (64 tagged units), retry until all
// tags == tag. Single-dword atomicity makes tag+value tear-free.
__device__ __forceinline__ void pollrow(const unsigned* base, unsigned tag, u32x4 (&d)[16]) {
  const unsigned tagw = tag << 16;
  for (int it = 0; it < POLL_CAP; ++it) {
#pragma unroll
    for (int ks = 0; ks < 8; ++ks) {
      d[2*ks]   = ld4_c(base + ks*32);
      d[2*ks+1] = ld4_c(base + ks*32 + 4);
    }
    waitv0(); sbar0();
    unsigned err = 0u;
#pragma unroll
    for (int i = 0; i < 16; ++i)
#pragma unroll
      for (int j = 0; j < 4; ++j)
        err |= (d[i][j] ^ tagw) & 0xffff0000u;
    if (__ballot(err == 0u) == ~0ull) return;
    __builtin_amdgcn_s_sleep(1);
  }
}
// dual-row variant (act1): both operand rows in one retry loop, one wait
__device__ __forceinline__ void pollrow2(const unsigned* ba, unsigned ta,
                                         const unsigned* bb, unsigned tb,
                                         u32x4 (&da)[16], u32x4 (&db)[16]) {
  const unsigned taw = ta << 16, tbw = tb << 16;
  for (int it = 0; it < POLL_CAP; ++it) {
#pragma unroll
    for (int ks = 0; ks < 8; ++ks) {
      da[2*ks]   = ld4_c(ba + ks*32);
      da[2*ks+1] = ld4_c(ba + ks*32 + 4);
      db[2*ks]   = ld4_c(bb + ks*32);
      db[2*ks+1] = ld4_c(bb + ks*32 + 4);
    }
    waitv0(); sbar0();
    unsigned err = 0u;
#pragma unroll
    for (int i = 0; i < 16; ++i)
#pragma unroll
      for (int j = 0; j < 4; ++j) {
        err |= (da[i][j] ^ taw) & 0xffff0000u;
        err |= (db[i][j] ^ tbw) & 0xffff0000u;
      }
    if (__ballot(err == 0u) == ~0ull) return;
    __builtin_amdgcn_s_sleep(1);
  }
}

// ---------------- prep: x -> bf16 ------------------
__global__ void k_prep_x(const float* __restrict__ x, __bf16* __restrict__ xbf) {
  int i = blockIdx.x * blockDim.x + threadIdx.x;
  const int n4 = (B_*T_*CIN)/4;
  if (i >= n4) return;
  float4 v = reinterpret_cast<const float4*>(x)[i];
  bf16x4 o;
  o[0] = (__bf16)v.x; o[1] = (__bf16)v.y; o[2] = (__bf16)v.z; o[3] = (__bf16)v.w;
  reinterpret_cast<bf16x4*>(xbf)[i] = o;
}

// ---------------- prep: weights into MFMA-fragment order ----------------
// target layout per matrix: [hj][ct][ks][sub][col][j]  (j=8 contiguous bf16)
// element = W[g=ct*256+hj*16+col][k=ks*32+sub*8+j]
__global__ void k_prep_w(const float* __restrict__ Wih0, const float* __restrict__ Whh0,
                         const float* __restrict__ Wih1, const float* __restrict__ Whh1,
                         __bf16* __restrict__ w0x, __bf16* __restrict__ w0h,
                         __bf16* __restrict__ w1x, __bf16* __restrict__ w1h) {
  int e = blockIdx.x * blockDim.x + threadIdx.x;
  const int E0 = G4*CIN, E1 = G4*H_;
  const float* W; __bf16* dst; int K; int idx;
  if      (e < E0)        { W = Wih0; dst = w0x; K = CIN; idx = e; }
  else if (e < E0+E1)     { W = Whh0; dst = w0h; K = H_;  idx = e - E0; }
  else if (e < E0+2*E1)   { W = Wih1; dst = w1x; K = H_;  idx = e - E0 - E1; }
  else if (e < E0+3*E1)   { W = Whh1; dst = w1h; K = H_;  idx = e - E0 - 2*E1; }
  else return;
  const int kb = K >> 5;                  // K/32
  int j   = idx & 7;
  int cl  = (idx >> 3) & 15;
  int sb  = (idx >> 7) & 3;
  int ks  = (idx >> 9) % kb;
  int ct  = (idx / (512*kb)) & 3;
  int hj  =  idx / (2048*kb);
  int g  = ct*256 + hj*16 + cl;
  int kk = ks*32 + sb*8 + j;
  dst[idx] = (__bf16)W[(size_t)g*K + kk];
}

// ---------------- prep: biases, zero pub rings (tags=0 = h_{-1}=0) ----------------
__global__ void k_prep_misc(const float* __restrict__ bih0, const float* __restrict__ bhh0,
                            const float* __restrict__ bih1, const float* __restrict__ bhh1,
                            float* __restrict__ bias0, float* __restrict__ bias1,
                            unsigned* __restrict__ zpub) {
  int i = blockIdx.x * blockDim.x + threadIdx.x;
  if (i < G4) bias0[i] = bih0[i] + bhh0[i];
  else if (i < 2*G4) { int j = i - G4; bias1[j] = bih1[j] + bhh1[j]; }
  const int PW = (int)((2*SZ_PUB)/4);
  int zi = i - 2*G4;
  if (zi >= 0 && zi < PW) zpub[zi] = 0u;   // apub+bpub contiguous
}

// ---------------- persistent pipelined LSTM (inline-tag sync) ----------------
// Iteration k: act0 computes h1_k (poll apub slot (k-1)&3 tag k), publishes
// apub slot k&3 tag k+1. act1 computes h2_{k-1} (poll apub tag k + bpub slot
// (k-2)&3 tag k-1), publishes bpub slot (k-1)&3 tag k. End barrier per WG
// makes 4-slot rings WAR-safe (see round-10 theory).
__global__ void __launch_bounds__(256, 1) k_lstm(
    const __bf16* __restrict__ xbf,
    const __bf16* __restrict__ w0x_g, const __bf16* __restrict__ w0h_g,
    const __bf16* __restrict__ w1x_g, const __bf16* __restrict__ w1h_g,
    const float* __restrict__ bias0, const float* __restrict__ bias1,
    unsigned* __restrict__ apub, unsigned* __restrict__ bpub,
    const float* __restrict__ Wfc, const float* __restrict__ bfc,
    float* __restrict__ out)
{
  extern __shared__ __bf16 lds[];
  __bf16* l0x = lds;                 // 4096  elems
  __bf16* l0h = lds + 4096;          // 16384
  __bf16* l1x = lds + 20480;         // 16384
  __bf16* l1h = lds + 36864;         // 16384
  __shared__ float s_log[MB][NC];

  const int tid   = threadIdx.x;
  const int bid   = blockIdx.x;
  const int bg    = bid & 7;         // L2-locality heuristic only
  const int hj    = bid >> 3;        // 0..15 hidden group
  const int wave  = tid >> 6;
  const int lane  = tid & 63;
  const int layer = wave >> 1;       // waves 0,1 -> layer0 ; waves 2,3 -> layer1
  const int mt    = wave & 1;
  const int col   = lane & 15;       // MFMA A-row / D-col index
  const int sub   = lane >> 4;       // MFMA k-group
  const int brow  = bg*MB + mt*16;

  // stage weights LDS-resident for the whole run
  {
    const uint4* s; uint4* d;
    s = (const uint4*)(w0x_g + (size_t)hj*4096);  d = (uint4*)l0x;
    for (int i = tid; i < 512;  i += 256) d[i] = s[i];
    s = (const uint4*)(w0h_g + (size_t)hj*16384); d = (uint4*)l0h;
    for (int i = tid; i < 2048; i += 256) d[i] = s[i];
    s = (const uint4*)(w1x_g + (size_t)hj*16384); d = (uint4*)l1x;
    for (int i = tid; i < 2048; i += 256) d[i] = s[i];
    s = (const uint4*)(w1h_g + (size_t)hj*16384); d = (uint4*)l1h;
    for (int i = tid; i < 2048; i += 256) d[i] = s[i];
  }
  __syncthreads();

  // per-lane gate biases (unit = hj*16+col), per this wave's layer
  float bs0, bs1, bs2, bs3;
  {
    const float* bp = layer ? bias1 : bias0;
    bs0 = bp[0*256 + hj*16 + col];
    bs1 = bp[1*256 + hj*16 + col];
    bs2 = bp[2*256 + hj*16 + col];
    bs3 = bp[3*256 + hj*16 + col];
  }
  float cst[4] = {0.f, 0.f, 0.f, 0.f};

  const size_t arow = (size_t)(brow + col)*H_ + sub*8;   // operand row offset (u32)

  for (int k = 0; k <= T_; ++k) {
    const unsigned* a_rd = apub + (size_t)((k+3)&3)*SLOT_U32;  // slot (k-1)&3
    unsigned*       a_wr = apub + (size_t)( k   &3)*SLOT_U32;  // slot k&3
    const unsigned* b_rd = bpub + (size_t)((k+2)&3)*SLOT_U32;  // slot (k-2)&3
    unsigned*       b_wr = bpub + (size_t)((k+3)&3)*SLOT_U32;  // slot (k-1)&3
    const bool act0 = (layer == 0) && (k < T_);
    const bool act1 = (layer == 1) && (k >= 1);
    f32x4 acc0 = {0,0,0,0}, acc1 = {0,0,0,0}, acc2 = {0,0,0,0}, acc3 = {0,0,0,0};

    // phase A (independent of published data): x-input GEMM, K=64
    if (act0) {
      const __bf16* xr = xbf + ((size_t)(brow+col)*T_ + k)*CIN + sub*8;
      const __bf16* wb = l0x + sub*128 + col*8;
#pragma unroll
      for (int ks = 0; ks < 2; ++ks) {
        bf16x8 a = *(const bf16x8*)(xr + ks*32);
        acc0 = MFMA(a, *(const bf16x8*)(wb + ks*512 +    0), acc0);
        acc1 = MFMA(a, *(const bf16x8*)(wb + ks*512 + 1024), acc1);
        acc2 = MFMA(a, *(const bf16x8*)(wb + ks*512 + 2048), acc2);
        acc3 = MFMA(a, *(const bf16x8*)(wb + ks*512 + 3072), acc3);
      }
    }

    // phase B: self-synchronizing poll-loads + recurrent GEMMs
    if (act0) {
      if (k > 0) {           // gates0 += a_{k-1} @ Whh0^T
        u32x4 d[16];
        pollrow(a_rd + arow, (unsigned)k, d);
        const __bf16* wb = l0h + sub*128 + col*8;
#pragma unroll
        for (int ks = 0; ks < 8; ++ks) {
          bf16x8 ar = packfrag(d[2*ks], d[2*ks+1]);
          acc0 = MFMA(ar, *(const bf16x8*)(wb + ks*512 +     0), acc0);
          acc1 = MFMA(ar, *(const bf16x8*)(wb + ks*512 +  4096), acc1);
          acc2 = MFMA(ar, *(const bf16x8*)(wb + ks*512 +  8192), acc2);
          acc3 = MFMA(ar, *(const bf16x8*)(wb + ks*512 + 12288), acc3);
        }
      }
    } else if (act1) {       // gates1 = a_{k-1} @ Wih1^T + b...h2_{k-2} @ Whh1^T
      u32x4 da[16], db[16];
      pollrow2(a_rd + arow, (unsigned)k, b_rd + arow, (unsigned)(k-1), da, db);
      const __bf16* w1 = l1x + sub*128 + col*8;
      const __bf16* w2 = l1h + sub*128 + col*8;
#pragma unroll
      for (int ks = 0; ks < 8; ++ks) {
        bf16x8 ar = packfrag(da[2*ks], da[2*ks+1]);
        acc0 = MFMA(ar, *(const bf16x8*)(w1 + ks*512 +     0), acc0);
        acc1 = MFMA(ar, *(const bf16x8*)(w1 + ks*512 +  4096), acc1);
        acc2 = MFMA(ar, *(const bf16x8*)(w1 + ks*512 +  8192), acc2);
        acc3 = MFMA(ar, *(const bf16x8*)(w1 + ks*512 + 12288), acc3);
      }
#pragma unroll
      for (int ks = 0; ks < 8; ++ks) {
        bf16x8 br = packfrag(db[2*ks], db[2*ks+1]);
        acc0 = MFMA(br, *(const bf16x8*)(w2 + ks*512 +     0), acc0);
        acc1 = MFMA(br, *(const bf16x8*)(w2 + ks*512 +  4096), acc1);
        acc2 = MFMA(br, *(const bf16x8*)(w2 + ks*512 +  8192), acc2);
        acc3 = MFMA(br, *(const bf16x8*)(w2 + ks*512 + 12288), acc3);
      }
    }

    // LSTM cell + tagged publish (4 x 4B stores/lane; no drain needed)
    if (act0 || act1) {
      unsigned* wr   = act0 ? a_wr : b_wr;
      unsigned  ptag = (act0 ? (unsigned)(k+1) : (unsigned)k) << 16;
      unsigned* base = wr + (size_t)(brow + sub*4)*H_ + hj*NHU + col;
#pragma unroll
      for (int q = 0; q < 4; ++q) {
        float gi = acc0[q] + bs0;
        float gf = acc1[q] + bs1;
        float gg = acc2[q] + bs2;
        float go = acc3[q] + bs3;
        float si = fsig(gi), sf = fsig(gf), sg = ftanh_(gg), so = fsig(go);
        float c = sf*cst[q] + si*sg;
        cst[q] = c;
        __bf16 hb = (__bf16)(so * ftanh_(c));
        unsigned w = ptag | (unsigned)__builtin_bit_cast(unsigned short, hb);
        st4_c(base + (size_t)q*H_, w);
      }
    }

    // end-of-iteration WG barrier: WAR-safety coupling for the 4-slot rings
    __syncthreads();
  }

  // ---------------- final FC + softmax (one WG per batch group) ----------------
  if (hj == 0) {
    // h2_{T-1}: bpub slot (T_-1)&3 == 3, tag T_
    if (tid < MB*NC) {
      int r = tid / NC, cl = tid % NC;
      const unsigned* hr = bpub + (size_t)3*SLOT_U32 + (size_t)(bg*MB + r)*H_;
      const float*  wr = Wfc + (size_t)cl*H_;
      const unsigned tagw = ((unsigned)T_) << 16;
      float s = bfc[cl];
      for (int c4 = 0; c4 < 64; ++c4) {
        u32x4 v;
        for (int it = 0; it < POLL_CAP; ++it) {
          v = ld4_c(hr + c4*4);
          waitv0();
          unsigned err = 0u;
#pragma unroll
          for (int j = 0; j < 4; ++j) err |= (v[j] ^ tagw) & 0xffff0000u;
          if (err == 0u) break;
          __builtin_amdgcn_s_sleep(1);
        }
#pragma unroll
        for (int j = 0; j < 4; ++j) {
          __bf16 hb = __builtin_bit_cast(__bf16, (unsigned short)(v[j] & 0xffffu));
          s = fmaf((float)hb, wr[c4*4+j], s);
        }
      }
      s_log[r][cl] = s;
    }
    __syncthreads();
    if (tid < MB) {
      float mx = s_log[tid][0];
#pragma unroll
      for (int c2 = 1; c2 < NC; ++c2) mx = fmaxf(mx, s_log[tid][c2]);
      float e[NC]; float se = 0.f;
#pragma unroll
      for (int c2 = 0; c2 < NC; ++c2) { e[c2] = __expf(s_log[tid][c2] - mx); se += e[c2]; }
      float inv = 1.f/se;
#pragma unroll
      for (int c2 = 0; c2 < NC; ++c2) out[(size_t)(bg*MB + tid)*NC + c2] = e[c2]*inv;
    }
  }
}

// ---------------- host launcher ----------------
extern "C" void kernel_launch(void* const* d_in, const int* in_sizes, int n_in,
                              void* d_out, int out_size, void* d_ws, size_t ws_size,
                              hipStream_t stream) {
  const float* x    = (const float*)d_in[0];
  const float* Wih0 = (const float*)d_in[1];
  const float* Whh0 = (const float*)d_in[2];
  const float* bih0 = (const float*)d_in[3];
  const float* bhh0 = (const float*)d_in[4];
  const float* Wih1 = (const float*)d_in[5];
  const float* Whh1 = (const float*)d_in[6];
  const float* bih1 = (const float*)d_in[7];
  const float* bhh1 = (const float*)d_in[8];
  const float* Wfc  = (const float*)d_in[9];
  const float* bfc  = (const float*)d_in[10];
  float* out = (float*)d_out;
  char*  ws  = (char*)d_ws;

  __bf16* xbf  = (__bf16*)(ws + OFF_XBF);
  __bf16* w0x  = (__bf16*)(ws + OFF_W0X);
  __bf16* w0h  = (__bf16*)(ws + OFF_W0H);
  __bf16* w1x  = (__bf16*)(ws + OFF_W1X);
  __bf16* w1h  = (__bf16*)(ws + OFF_W1H);
  float*  b0   = (float*) (ws + OFF_B0);
  float*  b1   = (float*) (ws + OFF_B1);
  unsigned* apub = (unsigned*)(ws + OFF_APUB);
  unsigned* bpub = (unsigned*)(ws + OFF_BPUB);

  {
    const int n4 = (B_*T_*CIN)/4;
    k_prep_x<<<(n4 + 255)/256, 256, 0, stream>>>(x, xbf);
  }
  {
    const int tot = G4*CIN + 3*G4*H_;
    k_prep_w<<<(tot + 255)/256, 256, 0, stream>>>(Wih0, Whh0, Wih1, Whh1, w0x, w0h, w1x, w1h);
  }
  {
    const int tot = 2*G4 + (int)((2*SZ_PUB)/4);
    k_prep_misc<<<(tot + 255)/256, 256, 0, stream>>>(bih0, bhh0, bih1, bhh1, b0, b1,
                                                     (unsigned*)apub);
  }
  (void)hipFuncSetAttribute((const void*)k_lstm,
                            hipFuncAttributeMaxDynamicSharedMemorySize, DYN_LDS_BYTES);
  k_lstm<<<NWG, 256, DYN_LDS_BYTES, stream>>>(xbf, w0x, w0h, w1x, w1h, b0, b1,
                                              apub, bpub, Wfc, bfc, out);
}